// Round 1
// baseline (318.223 us; speedup 1.0000x reference)
//
#include <hip/hip_runtime.h>
#include <math.h>

#define D_DIM 2048
#define D4    (D_DIM / 4)   // 512 float4 per row
#define NTOK  16384         // B*T
#define TPW   4             // tokens per wave
#define WPB   4             // waves per block (256 threads)
#define NW6   (NTOK * 6)    // 98304, size of weights (and of indices) chunk

// Router kernel: one wave handles TPW=4 tokens. Lane l covers elements
// {c*256 + l*4 .. +3} of the D=2048 dot; W fragments are register-cached and
// reused across the 4 tokens (4x less L1/L2 W traffic).
__global__ __launch_bounds__(256) void router_kernel(
    const float* __restrict__ x,
    const float* __restrict__ We,
    const float* __restrict__ Wg,
    float* __restrict__ out,
    unsigned int* __restrict__ gcounts)
{
    __shared__ unsigned int lcnt[16];
    const int tid = threadIdx.x;
    if (tid < 16) lcnt[tid] = 0u;
    __syncthreads();

    const int wave = tid >> 6;
    const int lane = tid & 63;
    const int tok0 = (blockIdx.x * WPB + wave) * TPW;

    float acc[18][TPW];
#pragma unroll
    for (int e = 0; e < 18; ++e)
#pragma unroll
        for (int t = 0; t < TPW; ++t) acc[e][t] = 0.f;

    const float4* __restrict__ x4  = reinterpret_cast<const float4*>(x);
    const float4* __restrict__ We4 = reinterpret_cast<const float4*>(We);
    const float4* __restrict__ Wg4 = reinterpret_cast<const float4*>(Wg);

#pragma unroll 2
    for (int c = 0; c < 8; ++c) {
        const int off = c * 64 + lane;
        float4 xv[TPW];
#pragma unroll
        for (int t = 0; t < TPW; ++t)
            xv[t] = x4[(size_t)(tok0 + t) * D4 + off];
#pragma unroll
        for (int e = 0; e < 16; ++e) {
            const float4 wv = We4[(size_t)e * D4 + off];
#pragma unroll
            for (int t = 0; t < TPW; ++t)
                acc[e][t] += wv.x * xv[t].x + wv.y * xv[t].y +
                             wv.z * xv[t].z + wv.w * xv[t].w;
        }
#pragma unroll
        for (int g = 0; g < 2; ++g) {
            const float4 wv = Wg4[(size_t)g * D4 + off];
#pragma unroll
            for (int t = 0; t < TPW; ++t)
                acc[16 + g][t] += wv.x * xv[t].x + wv.y * xv[t].y +
                                  wv.z * xv[t].z + wv.w * xv[t].w;
        }
    }

    // Butterfly-reduce each of the 72 partial sums across the 64 lanes.
#pragma unroll
    for (int e = 0; e < 18; ++e)
#pragma unroll
        for (int t = 0; t < TPW; ++t) {
            float v = acc[e][t];
#pragma unroll
            for (int m = 32; m >= 1; m >>= 1)
                v += __shfl_xor(v, m, 64);
            acc[e][t] = v;
        }

    // Lanes 0..3 do the scalar routing for token tok0+lane.
    if (lane < TPW) {
        const int tok = tok0 + lane;
        float s[16];
#pragma unroll
        for (int e = 0; e < 16; ++e) s[e] = acc[e][lane];
        const float g0 = 1.f / (1.f + expf(-acc[16][lane]));
        const float g1 = 1.f / (1.f + expf(-acc[17][lane]));

        // --- Group A: experts 0..7, top-1 of softmax ---
        int aidx = 0; float amax = s[0];
#pragma unroll
        for (int i = 1; i < 8; ++i)
            if (s[i] > amax) { amax = s[i]; aidx = i; }
        float asum = 0.f;
#pragma unroll
        for (int i = 0; i < 8; ++i) asum += expf(s[i] - amax);
        const float a_best = 1.f / asum;   // exp(0)/sum

        // --- Group B: experts 8..11, top-1, gated by g0 ---
        int bidx = 0; float bmax = s[8];
#pragma unroll
        for (int i = 1; i < 4; ++i)
            if (s[8 + i] > bmax) { bmax = s[8 + i]; bidx = i; }
        float bsum = 0.f;
#pragma unroll
        for (int i = 0; i < 4; ++i) bsum += expf(s[8 + i] - bmax);
        const float b_best = 1.f / bsum;
        const float b_w = (g0 > 0.15f) ? (b_best * g0) : 0.f;

        // --- Group C: experts 12..15, top-2 of softmax, gated by g1 ---
        int c1 = 0; float cmax = s[12];
#pragma unroll
        for (int i = 1; i < 4; ++i)
            if (s[12 + i] > cmax) { cmax = s[12 + i]; c1 = i; }
        float csum = 0.f;
#pragma unroll
        for (int i = 0; i < 4; ++i) csum += expf(s[12 + i] - cmax);
        int c2 = -1; float c2v = -1e30f;
#pragma unroll
        for (int i = 0; i < 4; ++i)
            if (i != c1 && s[12 + i] > c2v) { c2v = s[12 + i]; c2 = i; }
        const float cg   = (g1 > 0.15f) ? g1 : 0.f;
        const float c_w1 = (1.f / csum) * cg;                 // softmax at c1
        const float c_w2 = (expf(c2v - cmax) / csum) * cg;    // softmax at c2

        // --- normalize and write ---
        const float inv = 1.f / (a_best + b_w + c_w1 + c_w2 + 1e-8f);
        float* ow = out + (size_t)tok * 6;
        ow[0] = a_best * inv;
        ow[1] = b_w * inv;
        ow[2] = c_w1 * inv;
        ow[3] = c_w2 * inv;
        ow[4] = 0.f;
        ow[5] = 0.f;
        float* oi = out + NW6 + (size_t)tok * 6;
        oi[0] = (float)aidx;
        oi[1] = (float)(8 + bidx);
        oi[2] = (float)(12 + c1);
        oi[3] = (float)(12 + c2);
        oi[4] = 0.f;
        oi[5] = 0.f;

        atomicAdd(&lcnt[aidx], 1u);
        atomicAdd(&lcnt[8 + bidx], 1u);
        atomicAdd(&lcnt[12 + c1], 1u);
        atomicAdd(&lcnt[12 + c2], 1u);
    }

    __syncthreads();
    if (tid < 16 && lcnt[tid] != 0u) atomicAdd(&gcounts[tid], lcnt[tid]);
}

// Aux loss: counts include the 2 zero-pad indices per token -> index 0 gets
// +2*NTOK analytically. total = 6*NTOK. aux = sum u*(log u - log actual)*0.01.
__global__ void aux_kernel(const unsigned int* __restrict__ gcounts,
                           float* __restrict__ out)
{
    if (threadIdx.x == 0 && blockIdx.x == 0) {
        const float total = 6.0f * (float)NTOK;
        const float uni = 1.0f / 16.0f;
        float aux = 0.f;
        for (int e = 0; e < 16; ++e) {
            float c = (float)gcounts[e] + (e == 0 ? 2.0f * (float)NTOK : 0.0f);
            aux += uni * (logf(uni) - logf(c / total));
        }
        out[2 * NW6] = aux * 0.01f;
    }
}

extern "C" void kernel_launch(void* const* d_in, const int* in_sizes, int n_in,
                              void* d_out, int out_size, void* d_ws, size_t ws_size,
                              hipStream_t stream)
{
    const float* x  = (const float*)d_in[0];   // (4,4096,2048)
    const float* We = (const float*)d_in[1];   // (16,2048)
    const float* Wg = (const float*)d_in[2];   // (2,2048)
    float* out = (float*)d_out;                // weights | indices | aux
    unsigned int* counts = (unsigned int*)d_ws;

    hipMemsetAsync(counts, 0, 16 * sizeof(unsigned int), stream);

    const int blocks = NTOK / (TPW * WPB);     // 1024
    router_kernel<<<blocks, 256, 0, stream>>>(x, We, Wg, out, counts);
    aux_kernel<<<1, 64, 0, stream>>>(counts, out);
}

// Round 2
// 298.588 us; speedup vs baseline: 1.0658x; 1.0658x over previous
//
#include <hip/hip_runtime.h>
#include <math.h>

#define D_DIM 2048
#define D4    (D_DIM / 4)   // 512 float4 per row
#define NTOK  16384         // B*T
#define NW6   (NTOK * 6)    // weights (and indices) chunk size

// One wave = 4 groups of 16 lanes. Each group owns 2 tokens (8 tokens/wave).
// Each lane accumulates 18 expert dots for its 2 tokens in SCALAR registers
// (no dynamically-indexed arrays -> no scratch). W float4 fragments are
// loaded once per lane per chunk and reused for both tokens; the 4 groups
// read identical W addresses -> L1 broadcast.
__global__ __launch_bounds__(256) void router_kernel(
    const float* __restrict__ x,
    const float* __restrict__ We,
    const float* __restrict__ Wg,
    float* __restrict__ out,
    unsigned int* __restrict__ gcounts)
{
    __shared__ unsigned int lcnt[16];
    const int tid = threadIdx.x;
    if (tid < 16) lcnt[tid] = 0u;
    __syncthreads();

    const int wave = tid >> 6;
    const int lane = tid & 63;
    const int grp  = lane >> 4;   // 0..3
    const int l16  = lane & 15;   // position within group

    const int tok0 = (blockIdx.x * 4 + wave) * 8;   // 8 tokens per wave
    const int ta = tok0 + grp * 2;
    const int tb = ta + 1;

    const float4* __restrict__ x4  = reinterpret_cast<const float4*>(x);
    const float4* __restrict__ We4 = reinterpret_cast<const float4*>(We);
    const float4* __restrict__ Wg4 = reinterpret_cast<const float4*>(Wg);

    float acca[18], accb[18];
#pragma unroll
    for (int e = 0; e < 18; ++e) { acca[e] = 0.f; accb[e] = 0.f; }

    const float4* __restrict__ xa_p = x4 + (size_t)ta * D4;
    const float4* __restrict__ xb_p = x4 + (size_t)tb * D4;

    // Each group covers 16 float4 = 64 dims per iteration; 2048/64 = 32 iters.
#pragma unroll 2
    for (int c = 0; c < 32; ++c) {
        const int off = c * 16 + l16;
        const float4 xa = xa_p[off];
        const float4 xb = xb_p[off];
#pragma unroll
        for (int e = 0; e < 16; ++e) {
            const float4 wv = We4[(size_t)e * D4 + off];
            acca[e] += wv.x * xa.x + wv.y * xa.y + wv.z * xa.z + wv.w * xa.w;
            accb[e] += wv.x * xb.x + wv.y * xb.y + wv.z * xb.z + wv.w * xb.w;
        }
#pragma unroll
        for (int g = 0; g < 2; ++g) {
            const float4 wv = Wg4[(size_t)g * D4 + off];
            acca[16 + g] += wv.x * xa.x + wv.y * xa.y + wv.z * xa.z + wv.w * xa.w;
            accb[16 + g] += wv.x * xb.x + wv.y * xb.y + wv.z * xb.z + wv.w * xb.w;
        }
    }

    // Butterfly-reduce each sum across the 16 lanes of the group.
    // xor masks 1,2,4,8 never cross the 16-lane group boundary.
#pragma unroll
    for (int e = 0; e < 18; ++e) {
        float va = acca[e], vb = accb[e];
#pragma unroll
        for (int m = 8; m >= 1; m >>= 1) {
            va += __shfl_xor(va, m, 64);
            vb += __shfl_xor(vb, m, 64);
        }
        acca[e] = va; accb[e] = vb;
    }

    // Lanes l16==0 route token ta; l16==1 route token tb. Static selects only.
    if (l16 < 2) {
        const int tok = ta + l16;
        float s[16];
#pragma unroll
        for (int e = 0; e < 16; ++e) s[e] = (l16 == 0) ? acca[e] : accb[e];
        const float gs0 = (l16 == 0) ? acca[16] : accb[16];
        const float gs1 = (l16 == 0) ? acca[17] : accb[17];
        const float g0 = 1.f / (1.f + expf(-gs0));
        const float g1 = 1.f / (1.f + expf(-gs1));

        // --- Group A: experts 0..7, top-1 of softmax ---
        int aidx = 0; float amax = s[0];
#pragma unroll
        for (int i = 1; i < 8; ++i)
            if (s[i] > amax) { amax = s[i]; aidx = i; }
        float asum = 0.f;
#pragma unroll
        for (int i = 0; i < 8; ++i) asum += expf(s[i] - amax);
        const float a_best = 1.f / asum;

        // --- Group B: experts 8..11, top-1, gated by g0 ---
        int bidx = 0; float bmax = s[8];
#pragma unroll
        for (int i = 1; i < 4; ++i)
            if (s[8 + i] > bmax) { bmax = s[8 + i]; bidx = i; }
        float bsum = 0.f;
#pragma unroll
        for (int i = 0; i < 4; ++i) bsum += expf(s[8 + i] - bmax);
        const float b_w = (g0 > 0.15f) ? ((1.f / bsum) * g0) : 0.f;

        // --- Group C: experts 12..15, top-2 of softmax, gated by g1 ---
        int c1 = 0; float cmax = s[12];
#pragma unroll
        for (int i = 1; i < 4; ++i)
            if (s[12 + i] > cmax) { cmax = s[12 + i]; c1 = i; }
        float csum = 0.f;
#pragma unroll
        for (int i = 0; i < 4; ++i) csum += expf(s[12 + i] - cmax);
        int c2 = -1; float c2v = -1e30f;
#pragma unroll
        for (int i = 0; i < 4; ++i)
            if (i != c1 && s[12 + i] > c2v) { c2v = s[12 + i]; c2 = i; }
        const float cg   = (g1 > 0.15f) ? g1 : 0.f;
        const float c_w1 = (1.f / csum) * cg;
        const float c_w2 = (expf(c2v - cmax) / csum) * cg;

        // --- normalize and write (float2 vector stores, 8B-aligned) ---
        const float inv = 1.f / (a_best + b_w + c_w1 + c_w2 + 1e-8f);
        float2* ow = reinterpret_cast<float2*>(out + (size_t)tok * 6);
        ow[0] = make_float2(a_best * inv, b_w * inv);
        ow[1] = make_float2(c_w1 * inv, c_w2 * inv);
        ow[2] = make_float2(0.f, 0.f);
        float2* oi = reinterpret_cast<float2*>(out + NW6 + (size_t)tok * 6);
        oi[0] = make_float2((float)aidx, (float)(8 + bidx));
        oi[1] = make_float2((float)(12 + c1), (float)(12 + c2));
        oi[2] = make_float2(0.f, 0.f);

        atomicAdd(&lcnt[aidx], 1u);
        atomicAdd(&lcnt[8 + bidx], 1u);
        atomicAdd(&lcnt[12 + c1], 1u);
        atomicAdd(&lcnt[12 + c2], 1u);
    }

    __syncthreads();
    if (tid < 16 && lcnt[tid] != 0u) atomicAdd(&gcounts[tid], lcnt[tid]);
}

// Aux loss: reference bincount includes the 2 zero-pad indices per token ->
// expert 0 gets +2*NTOK analytically; total = 6*NTOK.
__global__ void aux_kernel(const unsigned int* __restrict__ gcounts,
                           float* __restrict__ out)
{
    if (threadIdx.x == 0 && blockIdx.x == 0) {
        const float total = 6.0f * (float)NTOK;
        const float uni = 1.0f / 16.0f;
        float aux = 0.f;
        for (int e = 0; e < 16; ++e) {
            float c = (float)gcounts[e] + (e == 0 ? 2.0f * (float)NTOK : 0.0f);
            aux += uni * (logf(uni) - logf(c / total));
        }
        out[2 * NW6] = aux * 0.01f;
    }
}

extern "C" void kernel_launch(void* const* d_in, const int* in_sizes, int n_in,
                              void* d_out, int out_size, void* d_ws, size_t ws_size,
                              hipStream_t stream)
{
    const float* x  = (const float*)d_in[0];   // (4,4096,2048)
    const float* We = (const float*)d_in[1];   // (16,2048)
    const float* Wg = (const float*)d_in[2];   // (2,2048)
    float* out = (float*)d_out;
    unsigned int* counts = (unsigned int*)d_ws;

    hipMemsetAsync(counts, 0, 16 * sizeof(unsigned int), stream);

    const int blocks = NTOK / (8 * 4);         // 8 tok/wave * 4 waves = 512
    router_kernel<<<blocks, 256, 0, stream>>>(x, We, Wg, out, counts);
    aux_kernel<<<1, 64, 0, stream>>>(counts, out);
}